// Round 15
// baseline (353.942 us; speedup 1.0000x reference)
//
#include <hip/hip_runtime.h>

#define HH 192
#define WW 192
#define HWPIX (HH * WW)
#define PLANE 5184           // 324 px * 16 B per c-octet plane
#define CHUNKB 20736         // 4 planes per 32c chunk

typedef __attribute__((ext_vector_type(8))) short bf16x8;
typedef __attribute__((ext_vector_type(4))) float f32x4;
typedef __attribute__((ext_vector_type(4))) unsigned int u32x4;

__device__ __forceinline__ unsigned f2bf(float f) {
    unsigned u = __builtin_bit_cast(unsigned, f);
    return (u + 0x7FFFu + ((u >> 16) & 1u)) >> 16;
}

__device__ __forceinline__ unsigned cvtpk(float lo, float hi) {
    unsigned r;
    asm("v_cvt_pk_bf16_f32 %0, %1, %2" : "=v"(r) : "v"(lo), "v"(hi));
    return r;
}

// ---------------- weight fusion (r7 layout, proven) ----------------
// frag = ((cc*3 + kw)*2 + mi)*12 + kh*4 + mo ; within frag: ln*8 + j
__global__ void fuse_weights(const float* __restrict__ wsq, const float* __restrict__ wv,
                             const float* __restrict__ whr, const float* __restrict__ w19,
                             const float* __restrict__ w37, unsigned short* __restrict__ wbuf) {
    int idx = blockIdx.x * 256 + threadIdx.x;
    if (idx >= 128 * 128 * 9) return;
    int o = idx / 1152;
    int r = idx - o * 1152;
    int c = r / 9;
    int tap = r - c * 9;
    int kh = tap / 3, kw = tap - kh * 3;
    float v = wsq[((o * 128 + c) * 3 + kh) * 3 + kw];
    if (kw == 1) v += wv[(o * 128 + c) * 3 + kh];
    if (kh == 1) v += whr[(o * 128 + c) * 3 + kw];
    if (kh == kw) v += w19[((o * 128 + c) * 3 + kh) * 3 + kw];
    if (kh + kw == 2) v += w37[((o * 128 + c) * 3 + kh) * 3 + kw];
    int cc = c >> 5;
    int mi = o >> 6, mo = (o >> 4) & 3;
    int ln = ((c >> 3) & 3) * 16 + (o & 15);
    int j = c & 7;
    int frag = ((cc * 3 + kw) * 2 + mi) * 12 + kh * 4 + mo;
    wbuf[(size_t)frag * 512 + ln * 8 + j] = (unsigned short)f2bf(v);
}

// ---------------- single-pass conv, A/B on staging only ----------------
// V=0: r7 scalar staging (8 scalar loads/px).  V=1: pixel-quad staging
// (task = 4px x 8c via 8 coalesced f32x4 loads; 13.5 vs 22.5 VMEM/thr/chunk).
// Everything else identical: 16x16 tile, 128 o, 4 waves (mi,ni), LDS
// [slot][px][16B], KWPASS kw-outer compute, epilogue, XCD swizzle.
template <int V>
__global__ __launch_bounds__(256, 2) void conv1t(const float* __restrict__ x,
                                                 const unsigned short* __restrict__ wbuf,
                                                 float* __restrict__ out, int b0) {
    __shared__ __align__(1024) unsigned char lds[2 * CHUNKB];
    const int t = threadIdx.x, l = t & 63, wvid = t >> 6;
    const int mi = wvid >> 1, ni = wvid & 1, l15 = l & 15, l4 = l >> 4;

    // XCD swizzle: 1152 = 8 x 144 (1 batch-set per XCD pass)
    int id = (int)blockIdx.x;
    int id2 = (id & 7) * 144 + (id >> 3);
    int bl = id2 / 144;
    int rem = id2 - bl * 144;
    int by = rem / 12, bx = rem - by * 12;
    const int h0 = by * 16, w0 = bx * 16;
    const int b = b0 + bl;

    const float* __restrict__ xb = x + (size_t)b * (128 * HWPIX);

    f32x4 acc[4][8];
    const f32x4 zero = {0.f, 0.f, 0.f, 0.f};
#pragma unroll
    for (int mo = 0; mo < 4; ++mo)
#pragma unroll
        for (int np = 0; np < 8; ++np) acc[mo][np] = zero;

    // ---- V0 staging state (r7 verbatim) ----
    float sv[4][8];
    int sok[4];
    // ---- V1 staging state ----
    f32x4 qvA[8], qvB[8];

#define LOADH(CC, H)                                                                    \
    _Pragma("unroll") for (int k = 0; k < 4; ++k) {                                     \
        const int item = (H) * 4 + k;                                                   \
        const int slot = item >> 1;                                                     \
        int px = (item & 1) * 256 + t;                                                  \
        if (px < 324) {                                                                 \
            int ih = px / 18, iw = px - ih * 18;                                        \
            int gh = h0 - 1 + ih, gw = w0 - 1 + iw;                                     \
            sok[k] = ((unsigned)gh < (unsigned)HH) & ((unsigned)gw < (unsigned)WW);     \
            int ghc = min(max(gh, 0), HH - 1), gwc = min(max(gw, 0), WW - 1);           \
            const float* p = xb + (size_t)((CC) * 32 + slot * 8) * HWPIX + ghc * WW + gwc; \
            _Pragma("unroll") for (int j = 0; j < 8; ++j) sv[k][j] = p[j * HWPIX];      \
        }                                                                               \
    }

#define WRITEH(H, BB)                                                                   \
    _Pragma("unroll") for (int k = 0; k < 4; ++k) {                                     \
        const int item = (H) * 4 + k;                                                   \
        const int slot = item >> 1;                                                     \
        int px = (item & 1) * 256 + t;                                                  \
        if (px < 324) {                                                                 \
            u32x4 pk;                                                                   \
            _Pragma("unroll") for (int q = 0; q < 4; ++q) {                             \
                unsigned v_ = cvtpk(sv[2 * q >> 1][0], sv[0][0]);                       \
                (void)v_;                                                               \
                float lo = sok[k] ? sv[k][2 * q] : 0.f;                                 \
                float hi = sok[k] ? sv[k][2 * q + 1] : 0.f;                             \
                pk[q] = cvtpk(lo, hi);                                                  \
            }                                                                           \
            *(u32x4*)(lds + (BB) + slot * PLANE + px * 16) = pk;                        \
        }                                                                               \
    }

    // V1: task tau = t+256*R < 432: oct = tau/108, row = (tau%108)/6, quad = %6
#define LOADQ(CC, R, QV)                                                                \
    {                                                                                   \
        int tau = t + 256 * (R);                                                        \
        if ((R) == 0 || tau < 432) {                                                    \
            int oct = tau / 108;                                                        \
            int r6 = tau - oct * 108;                                                   \
            int row = r6 / 6, quad = r6 - row * 6;                                      \
            int gh = h0 - 1 + row;                                                      \
            int ghc_ = min(max(gh, 0), HH - 1);                                         \
            int gwb = w0 - 4 + 4 * quad;                                                \
            int gwc_ = min(max(gwb, 0), WW - 4);                                        \
            const float* p_ = xb + (size_t)((CC) * 32 + oct * 8) * HWPIX + ghc_ * WW + gwc_; \
            _Pragma("unroll") for (int j = 0; j < 8; ++j)                               \
                QV[j] = *(const f32x4*)(p_ + (size_t)j * HWPIX);                        \
        }                                                                               \
    }

#define WRITEQ(R, BB, QV)                                                               \
    {                                                                                   \
        int tau = t + 256 * (R);                                                        \
        if ((R) == 0 || tau < 432) {                                                    \
            int oct = tau / 108;                                                        \
            int r6 = tau - oct * 108;                                                   \
            int row = r6 / 6, quad = r6 - row * 6;                                      \
            int gh = h0 - 1 + row;                                                      \
            int hok_ = (unsigned)gh < (unsigned)HH;                                     \
            int gwb = w0 - 4 + 4 * quad;                                                \
            _Pragma("unroll") for (int e = 0; e < 4; ++e) {                             \
                int gw = gwb + e;                                                       \
                int iw = gw - (w0 - 1);                                                 \
                if ((unsigned)iw < 18u) {                                               \
                    int ok_ = hok_ & ((unsigned)gw < (unsigned)WW);                     \
                    u32x4 pk;                                                           \
                    _Pragma("unroll") for (int q = 0; q < 4; ++q) {                     \
                        float lo = ok_ ? QV[2 * q][e] : 0.f;                            \
                        float hi = ok_ ? QV[2 * q + 1][e] : 0.f;                        \
                        pk[q] = cvtpk(lo, hi);                                          \
                    }                                                                   \
                    int px = row * 18 + iw;                                             \
                    *(u32x4*)(lds + (BB) + oct * PLANE + px * 16) = pk;                 \
                }                                                                       \
            }                                                                           \
        }                                                                               \
    }

#define KWPASS(KW)                                                                      \
    {                                                                                   \
        const unsigned short* wp =                                                      \
            wbuf + (size_t)(((cc * 3 + (KW)) * 2 + mi) * 12) * 512 + l * 8;             \
        bf16x8 a[12];                                                                   \
        _Pragma("unroll") for (int f = 0; f < 12; ++f)                                  \
            a[f] = *(const bf16x8*)(wp + f * 512);                                      \
        _Pragma("unroll") for (int rr = 0; rr < 10; ++rr) {                             \
            bf16x8 bf = *(const bf16x8*)(lds + bb + l4 * PLANE +                        \
                                         (ni * 144 + l15) * 16 + (KW) * 16 + rr * 288); \
            _Pragma("unroll") for (int kh = 0; kh < 3; ++kh) {                          \
                const int np = rr - kh;                                                 \
                if (np >= 0 && np < 8) {                                                \
                    _Pragma("unroll") for (int mo = 0; mo < 4; ++mo)                    \
                        acc[mo][np] = __builtin_amdgcn_mfma_f32_16x16x32_bf16(          \
                            a[kh * 4 + mo], bf, acc[mo][np], 0, 0, 0);                  \
                }                                                                       \
            }                                                                           \
        }                                                                               \
    }

    // prologue: stage chunk 0 into buffer 0
    if (V == 0) {
        LOADH(0, 0) WRITEH(0, 0)
        LOADH(0, 1) WRITEH(1, 0)
    } else {
        LOADQ(0, 0, qvA) WRITEQ(0, 0, qvA)
        LOADQ(0, 1, qvB) WRITEQ(1, 0, qvB)
    }
    __syncthreads();

    int bb = 0;
#pragma unroll 1
    for (int cc = 0; cc < 4; ++cc) {
        if (V == 0) {
            if (cc < 3) { LOADH(cc + 1, 0) }
            KWPASS(0)
            if (cc < 3) {
                WRITEH(0, bb ^ CHUNKB)
                LOADH(cc + 1, 1)
            }
            KWPASS(1)
            if (cc < 3) { WRITEH(1, bb ^ CHUNKB) }
            KWPASS(2)
        } else {
            if (cc < 3) { LOADQ(cc + 1, 0, qvA) }
            KWPASS(0)
            if (cc < 3) {
                WRITEQ(0, bb ^ CHUNKB, qvA)
                LOADQ(cc + 1, 1, qvB)
            }
            KWPASS(1)
            if (cc < 3) { WRITEQ(1, bb ^ CHUNKB, qvB) }
            KWPASS(2)
        }
        __syncthreads();
        bb ^= CHUNKB;
    }

    // epilogue: D row=(l>>4)*4+j -> o, col=l&15 -> w  (r7 verbatim)
    float* __restrict__ ob = out + (size_t)b * (128 * HWPIX) + (size_t)h0 * WW + w0 + l15;
#pragma unroll
    for (int mo = 0; mo < 4; ++mo) {
#pragma unroll
        for (int j = 0; j < 4; ++j) {
            int o = mi * 64 + mo * 16 + l4 * 4 + j;
            float* op = ob + (size_t)o * HWPIX;
#pragma unroll
            for (int np = 0; np < 8; ++np)
                op[(ni * 8 + np) * WW] = acc[mo][np][j];
        }
    }
}

extern "C" void kernel_launch(void* const* d_in, const int* in_sizes, int n_in,
                              void* d_out, int out_size, void* d_ws, size_t ws_size,
                              hipStream_t stream) {
    const float* x   = (const float*)d_in[0];
    const float* wsq = (const float*)d_in[1];
    const float* wvv = (const float*)d_in[2];
    const float* wh  = (const float*)d_in[3];
    const float* w19 = (const float*)d_in[4];
    const float* w37 = (const float*)d_in[5];

    unsigned short* wbuf = (unsigned short*)d_ws;  // 294,912 B

    fuse_weights<<<576, 256, 0, stream>>>(wsq, wvv, wh, w19, w37, wbuf);
    conv1t<0><<<1152, 256, 0, stream>>>(x, wbuf, (float*)d_out, 0);   // batches 0-7
    conv1t<1><<<1152, 256, 0, stream>>>(x, wbuf, (float*)d_out, 8);   // batches 8-15
}